// Round 2
// baseline (2850.231 us; speedup 1.0000x reference)
//
#include <hip/hip_runtime.h>
#include <cstdint>
#include <cstddef>

#define T_DIM 4
#define B_DIM 32
#define C_DIM 256
#define N_DIM 1024
#define NHEAD 8
#define DHEAD 32
#define NWRD 32   // N/32 bit-words per row

typedef float f32x16 __attribute__((ext_vector_type(16)));

// LIF step, exact reference rounding: v += (x-v)/2; s = v>=vth; hard reset.
__device__ __forceinline__ float lif_step(float& v, float x, float vth) {
    v = __fadd_rn(v, __fmul_rn(__fsub_rn(x, v), 0.5f));
    const float s = (v >= vth) ? 1.0f : 0.0f;
    if (s != 0.0f) v = 0.0f;
    return s;
}

// async global->LDS, 16B per lane. LDS dest = wave-uniform base + lane*16.
__device__ __forceinline__ void async_copy16(const float* g, float* l) {
    __builtin_amdgcn_global_load_lds(
        (const __attribute__((address_space(1))) unsigned int*)g,
        (__attribute__((address_space(3))) unsigned int*)l, 16, 0, 0);
}

// ---- k-step: A (16 wave-uniform floats x 2 k-rows) via fused
// s_load_dwordx16 pair + lgkmcnt(0) drain IN ONE asm (values architecturally
// valid at asm end -> no cross-asm in-flight register hazards). B from LDS via
// plain C++ (compiler-tracked waits). Strict k-ascending fmaf chains per acc.
#define KSTEP2(KK, WST) { \
    f32x16 A0, A1; \
    asm volatile("s_load_dwordx16 %0, %2, %3\n\t" \
                 "s_load_dwordx16 %1, %2, %4\n\t" \
                 "s_waitcnt lgkmcnt(0)" \
                 : "=&s"(A0), "=&s"(A1) \
                 : "s"(wb), "n"((KK) * (WST)), "n"(((KK) + 1) * (WST))); \
    const float b0A = xl[(KK) * 128 + l]; \
    const float b0B = xl[(KK) * 128 + 64 + l]; \
    const float b1A = xl[(KK) * 128 + 128 + l]; \
    const float b1B = xl[(KK) * 128 + 192 + l]; \
    _Pragma("unroll") \
    for (int r_ = 0; r_ < 16; ++r_) { \
        acc[r_ * 2]     = fmaf(A0[r_], b0A, acc[r_ * 2]); \
        acc[r_ * 2 + 1] = fmaf(A0[r_], b0B, acc[r_ * 2 + 1]); \
    } \
    _Pragma("unroll") \
    for (int r_ = 0; r_ < 16; ++r_) { \
        acc[r_ * 2]     = fmaf(A1[r_], b1A, acc[r_ * 2]); \
        acc[r_ * 2 + 1] = fmaf(A1[r_], b1B, acc[r_ * 2 + 1]); \
    } }

#define KLOOP(WST) \
    KSTEP2(0, WST)  KSTEP2(2, WST)  KSTEP2(4, WST)  KSTEP2(6, WST) \
    KSTEP2(8, WST)  KSTEP2(10, WST) KSTEP2(12, WST) KSTEP2(14, WST) \
    KSTEP2(16, WST) KSTEP2(18, WST) KSTEP2(20, WST) KSTEP2(22, WST) \
    KSTEP2(24, WST) KSTEP2(26, WST) KSTEP2(28, WST) KSTEP2(30, WST)

// Pre-transpose: wqk_t[k][h*64+j] = (j<32 ? qw[h*32+j][k] : kw[h*32+j-32][k])
//                p_t[k][c] = pw[c][k]
__global__ __launch_bounds__(256) void k_transpose(
    const float* __restrict__ qw, const float* __restrict__ kw,
    const float* __restrict__ pw, float* __restrict__ wqk_t,
    float* __restrict__ p_t)
{
    const int i = blockIdx.x * 256 + threadIdx.x;
    if (i < C_DIM * 512) {
        const int k = i >> 9, col = i & 511;
        const int h = col >> 6, j = col & 63;
        wqk_t[i] = (j < 32) ? qw[(size_t)(h * 32 + j) * C_DIM + k]
                            : kw[(size_t)(h * 32 + j - 32) * C_DIM + k];
    } else {
        const int i2 = i - C_DIM * 512;            // < 65536
        const int k = i2 >> 8, c = i2 & 255;
        p_t[i2] = pw[(size_t)c * C_DIM + k];
    }
}

// K1: one head per block, block tile m=64 (4 waves x 16-row stripes:
// [Q0..15][Q16..31][K0..15][K16..31]), n=128. A from SGPR s_load, B from LDS.
// grid (N/128, B, NHEAD): the 8 head-blocks sharing an x-slice have linear-id
// stride 256 === 0 mod 8 -> same XCD -> L2 reuse of x.
__global__ __launch_bounds__(256, 4) void k_qk(
    const float* __restrict__ x, const float* __restrict__ wqk,   // [256][512]
    const float* __restrict__ qg, const float* __restrict__ qbeta,
    const float* __restrict__ qmean, const float* __restrict__ qvar,
    const float* __restrict__ kg, const float* __restrict__ kbeta,
    const float* __restrict__ kmean, const float* __restrict__ kvar,
    uint32_t* __restrict__ xbits)
{
    __shared__ float x_lds[2][32 * 128];   // [buf][k][n] 2x16 KB
    __shared__ float inv_lds[64];
    __shared__ float bias_lds[64];
    __shared__ float qpart_lds[2][128];    // Q half-stripe sums per col

    const int tid = threadIdx.x;
    const int nt = blockIdx.x, b = blockIdx.y, h = blockIdx.z;
    const int n0g = nt * 128;
    const int l   = tid & 63;
    const int sw  = __builtin_amdgcn_readfirstlane(tid >> 6);   // stripe/wave id
    const bool is_q = (sw < 2);

    if (tid < 64) {
        const int j = tid;
        const bool q = (j < 32);
        const float* gp = q ? qg    : kg;
        const float* be = q ? qbeta : kbeta;
        const float* me = q ? qmean : kmean;
        const float* va = q ? qvar  : kvar;
        const int ch = h * DHEAD + (q ? j : j - 32);
        const float iv = __fdiv_rn(gp[ch], __fsqrt_rn(__fadd_rn(va[ch], 1e-5f)));
        inv_lds[j]  = iv;
        bias_lds[j] = __fsub_rn(be[ch], __fmul_rn(me[ch], iv));
    }

    const int skl  = tid >> 5;
    const int scol = (tid & 31) << 2;

    float vstate[32];
    #pragma unroll
    for (int i = 0; i < 32; ++i) vstate[i] = 0.0f;
    float v_attn0 = 0.0f, v_attn1 = 0.0f;
    float acc[32];
    #pragma unroll
    for (int i = 0; i < 32; ++i) acc[i] = 0.0f;

    // stage x chunk 0 into buf 0
    {
        const float* xgp = x + ((size_t)b * C_DIM + skl) * N_DIM + n0g + scol;
        #pragma unroll
        for (int r = 0; r < 4; ++r)
            async_copy16(xgp + (size_t)(r * 8) * N_DIM, &x_lds[0][r * 1024 + tid * 4]);
    }

    const size_t woff = (size_t)h * 64 + (size_t)sw * 16;   // stripe cols in wqk_t

    #pragma unroll 1
    for (int gi = 0; gi < 32; ++gi) {
        const int cur = gi & 1;
        __syncthreads();   // drains x-stage(gi) [vmcnt]; joins buf readers
        if (gi + 1 < 32) { // stage x chunk gi+1 into the other buffer
            const int g1 = gi + 1, tt = g1 >> 3, kk = (g1 & 7) * 32;
            const float* xgp = x + ((size_t)(tt * B_DIM + b) * C_DIM + kk + skl) * N_DIM
                               + n0g + scol;
            float* xd = &x_lds[1 - cur][0];
            #pragma unroll
            for (int r = 0; r < 4; ++r)
                async_copy16(xgp + (size_t)(r * 8) * N_DIM, xd + r * 1024 + tid * 4);
        }
        {
            const float* wb = wqk + (size_t)((gi & 7) * 32) * 512 + woff;
            const float* xl = &x_lds[cur][0];
            KLOOP(2048)
        }

        if ((gi & 7) == 7) {   // end of one t: BN + LIF + attn + ballot-pack
            const int t = gi >> 3;
            #pragma unroll
            for (int r = 0; r < 16; ++r) {
                const float iv = inv_lds[sw * 16 + r];
                const float bs = bias_lds[sw * 16 + r];
                const float y0 = __fadd_rn(__fmul_rn(acc[r * 2],     iv), bs);
                const float y1 = __fadd_rn(__fmul_rn(acc[r * 2 + 1], iv), bs);
                acc[r * 2]     = lif_step(vstate[r * 2],     y0, 1.0f);
                acc[r * 2 + 1] = lif_step(vstate[r * 2 + 1], y1, 1.0f);
            }
            if (is_q) {   // lane-local half-sums (exact integers, order-free)
                float pA = acc[0], pB = acc[1];
                #pragma unroll
                for (int r = 1; r < 16; ++r) { pA += acc[r * 2]; pB += acc[r * 2 + 1]; }
                qpart_lds[sw][l]      = pA;
                qpart_lds[sw][64 + l] = pB;
            }
            __syncthreads();
            if (!is_q) {   // both K-waves: attn LIF (identical, deterministic)
                const float qA = qpart_lds[0][l]      + qpart_lds[1][l];
                const float qB = qpart_lds[0][64 + l] + qpart_lds[1][64 + l];
                const float aA = lif_step(v_attn0, qA, 0.5f);
                const float aB = lif_step(v_attn1, qB, 0.5f);
                uint64_t k0 = 0ull, k1 = 0ull;
                #pragma unroll
                for (int r = 0; r < 16; ++r) {
                    const uint64_t m0 = __ballot(acc[r * 2]     != 0.0f && aA != 0.0f);
                    const uint64_t m1 = __ballot(acc[r * 2 + 1] != 0.0f && aB != 0.0f);
                    if (l == r) { k0 = m0; k1 = m1; }
                }
                if (l < 16) {   // lane l stores row l's 4 words
                    const int ch = h * DHEAD + (sw - 2) * 16 + l;
                    uint4 v;
                    v.x = (uint32_t)k0; v.y = (uint32_t)(k0 >> 32);
                    v.z = (uint32_t)k1; v.w = (uint32_t)(k1 >> 32);
                    *(uint4*)&xbits[(((size_t)t * B_DIM + b) * C_DIM + ch) * NWRD + nt * 4] = v;
                }
            }
            #pragma unroll
            for (int i = 0; i < 32; ++i) acc[i] = 0.0f;
        }
    }
}

// K2: projection GEMM. block tile m=64 (4 x 16-row stripes), n=128.
// grid (C/64, N/128, B) = 1024 blocks = exactly one resident round at 4/CU.
__global__ __launch_bounds__(256, 4) void k_proj(
    const uint32_t* __restrict__ xbits, const float* __restrict__ pt,  // [256][256]
    const float* __restrict__ pbias, const float* __restrict__ pg,
    const float* __restrict__ pbeta, const float* __restrict__ pmean,
    const float* __restrict__ pvar, float* __restrict__ out)
{
    __shared__ float x_lds[2][32 * 128];
    __shared__ float inv_lds[64];
    __shared__ float bias_lds[64];
    __shared__ float pb_lds[64];

    const int tid = threadIdx.x;
    const int mt = blockIdx.x, nt = blockIdx.y, b = blockIdx.z;
    const int n0g = nt * 128;
    const int c0  = mt * 64;
    const int l   = tid & 63;
    const int sw  = __builtin_amdgcn_readfirstlane(tid >> 6);

    if (tid < 64) {
        const int ch = c0 + tid;
        const float iv = __fdiv_rn(pg[ch], __fsqrt_rn(__fadd_rn(pvar[ch], 1e-5f)));
        inv_lds[tid]  = iv;
        bias_lds[tid] = __fsub_rn(pbeta[ch], __fmul_rn(pmean[ch], iv));
        pb_lds[tid]   = pbias[ch];
    }

    // unpack: thread -> chunk k-row urow (0..31), 16 cols at cg*16
    const int urow = tid >> 3, cg = tid & 7;
    const int wsel = nt * 4 + (cg >> 1);
    const int ushf = (cg & 1) * 16;

    float vstate[32];
    #pragma unroll
    for (int i = 0; i < 32; ++i) vstate[i] = 0.0f;
    float acc[32];
    #pragma unroll
    for (int i = 0; i < 32; ++i) acc[i] = 0.0f;

    #define BITS_AT(G) xbits[((size_t)((G) >> 3) * B_DIM + b) * C_DIM * NWRD \
                             + (size_t)(((G) & 7) * 32 + urow) * NWRD + wsel]

    // prologue: unpack chunk 0 into buf0; preload bits(1)
    {
        const uint32_t u0 = BITS_AT(0);
        const uint32_t bits = (u0 >> ushf) & 0xffffu;
        float* xw = &x_lds[0][tid * 16];
        #pragma unroll
        for (int q4 = 0; q4 < 4; ++q4) {
            float4 f;
            f.x = ((bits >> (q4 * 4 + 0)) & 1u) ? 1.0f : 0.0f;
            f.y = ((bits >> (q4 * 4 + 1)) & 1u) ? 1.0f : 0.0f;
            f.z = ((bits >> (q4 * 4 + 2)) & 1u) ? 1.0f : 0.0f;
            f.w = ((bits >> (q4 * 4 + 3)) & 1u) ? 1.0f : 0.0f;
            *(float4*)(xw + q4 * 4) = f;
        }
    }
    uint32_t u_a = BITS_AT(1);

    const size_t woff = (size_t)c0 + (size_t)sw * 16;

    #pragma unroll 1
    for (int gi = 0; gi < 32; ++gi) {
        const int cur = gi & 1;
        __syncthreads();
        if (gi + 1 < 32) {  // unpack chunk gi+1 into the other buffer
            const uint32_t bits = (u_a >> ushf) & 0xffffu;
            float* xw = &x_lds[1 - cur][tid * 16];
            #pragma unroll
            for (int q4 = 0; q4 < 4; ++q4) {
                float4 f;
                f.x = ((bits >> (q4 * 4 + 0)) & 1u) ? 1.0f : 0.0f;
                f.y = ((bits >> (q4 * 4 + 1)) & 1u) ? 1.0f : 0.0f;
                f.z = ((bits >> (q4 * 4 + 2)) & 1u) ? 1.0f : 0.0f;
                f.w = ((bits >> (q4 * 4 + 3)) & 1u) ? 1.0f : 0.0f;
                *(float4*)(xw + q4 * 4) = f;
            }
        }
        if (gi + 2 < 32) u_a = BITS_AT(gi + 2);   // hidden under compute(gi)
        {
            const float* wb = pt + (size_t)((gi & 7) * 32) * 256 + woff;
            const float* xl = &x_lds[cur][0];
            KLOOP(1024)
        }

        if ((gi & 7) == 7) {   // end of t: bias + BN + LIF + store
            const int t = gi >> 3;
            #pragma unroll
            for (int r = 0; r < 16; ++r) {
                const int m = sw * 16 + r;
                const float iv = inv_lds[m];
                const float bs = bias_lds[m];
                const float pb = pb_lds[m];
                float y0 = __fadd_rn(acc[r * 2],     pb);
                float y1 = __fadd_rn(acc[r * 2 + 1], pb);
                y0 = __fadd_rn(__fmul_rn(y0, iv), bs);
                y1 = __fadd_rn(__fmul_rn(y1, iv), bs);
                const float s0 = lif_step(vstate[r * 2],     y0, 1.0f);
                const float s1 = lif_step(vstate[r * 2 + 1], y1, 1.0f);
                float* ob = out + (((size_t)t * B_DIM + b) * C_DIM + c0 + m) * N_DIM + n0g;
                ob[l]      = s0;
                ob[64 + l] = s1;
            }
            #pragma unroll
            for (int i = 0; i < 32; ++i) acc[i] = 0.0f;
        }
    }
    #undef BITS_AT
}

extern "C" void kernel_launch(void* const* d_in, const int* in_sizes, int n_in,
                              void* d_out, int out_size, void* d_ws, size_t ws_size,
                              hipStream_t stream) {
    const float* x    = (const float*)d_in[0];
    const float* q_w  = (const float*)d_in[1];
    const float* q_g  = (const float*)d_in[2];
    const float* q_b  = (const float*)d_in[3];
    const float* q_m  = (const float*)d_in[4];
    const float* q_v  = (const float*)d_in[5];
    const float* k_w  = (const float*)d_in[6];
    const float* k_g  = (const float*)d_in[7];
    const float* k_b  = (const float*)d_in[8];
    const float* k_m  = (const float*)d_in[9];
    const float* k_v  = (const float*)d_in[10];
    const float* p_w  = (const float*)d_in[11];
    const float* p_b  = (const float*)d_in[12];
    const float* p_g  = (const float*)d_in[13];
    const float* p_be = (const float*)d_in[14];
    const float* p_m  = (const float*)d_in[15];
    const float* p_v  = (const float*)d_in[16];

    // ws layout: wqk_t 512KB | p_t 256KB | xbits 4MB
    float*    wqk_t = (float*)d_ws;
    float*    p_t   = (float*)((char*)d_ws + 524288);
    uint32_t* xbits = (uint32_t*)((char*)d_ws + 786432);
    float*    out   = (float*)d_out;

    k_transpose<<<768, 256, 0, stream>>>(q_w, k_w, p_w, wqk_t, p_t);

    dim3 g1(N_DIM / 128, B_DIM, NHEAD);
    k_qk<<<g1, 256, 0, stream>>>(x, wqk_t, q_g, q_b, q_m, q_v,
                                 k_g, k_b, k_m, k_v, xbits);

    dim3 g2(C_DIM / 64, N_DIM / 128, B_DIM);
    k_proj<<<g2, 256, 0, stream>>>(xbits, p_t, p_b, p_g, p_be, p_m, p_v, out);
}

// Round 3
// 994.980 us; speedup vs baseline: 2.8646x; 2.8646x over previous
//
#include <hip/hip_runtime.h>
#include <cstdint>
#include <cstddef>

#define T_DIM 4
#define B_DIM 32
#define C_DIM 256
#define N_DIM 1024
#define NHEAD 8
#define DHEAD 32
#define NWRD 32   // N/32 bit-words per row

// LIF step, exact reference rounding: v += (x-v)/2; s = v>=vth; hard reset.
__device__ __forceinline__ float lif_step(float& v, float x, float vth) {
    v = __fadd_rn(v, __fmul_rn(__fsub_rn(x, v), 0.5f));
    const float s = (v >= vth) ? 1.0f : 0.0f;
    if (s != 0.0f) v = 0.0f;
    return s;
}

// async global->LDS, 16B per lane. LDS dest = wave-uniform base + lane*16.
__device__ __forceinline__ void async_copy16(const float* g, float* l) {
    __builtin_amdgcn_global_load_lds(
        (const __attribute__((address_space(1))) unsigned int*)g,
        (__attribute__((address_space(3))) unsigned int*)l, 16, 0, 0);
}

// one a-element times 8 cols (two float4 col-quads), strict k-ascending chains
#define FMA_ROW(r, av)                                \
    acc[(r)*8+0] = fmaf(av, b0.x, acc[(r)*8+0]);      \
    acc[(r)*8+1] = fmaf(av, b0.y, acc[(r)*8+1]);      \
    acc[(r)*8+2] = fmaf(av, b0.z, acc[(r)*8+2]);      \
    acc[(r)*8+3] = fmaf(av, b0.w, acc[(r)*8+3]);      \
    acc[(r)*8+4] = fmaf(av, b1.x, acc[(r)*8+4]);      \
    acc[(r)*8+5] = fmaf(av, b1.y, acc[(r)*8+5]);      \
    acc[(r)*8+6] = fmaf(av, b1.z, acc[(r)*8+6]);      \
    acc[(r)*8+7] = fmaf(av, b1.w, acc[(r)*8+7]);

#define FMA_8x8()        \
    FMA_ROW(0, a0.x)     \
    FMA_ROW(1, a0.y)     \
    FMA_ROW(2, a0.z)     \
    FMA_ROW(3, a0.w)     \
    FMA_ROW(4, a1.x)     \
    FMA_ROW(5, a1.y)     \
    FMA_ROW(6, a1.z)     \
    FMA_ROW(7, a1.w)

// Pre-transpose: wqk_t[k][h*64+j] = (j<32 ? qw[h*32+j][k] : kw[h*32+j-32][k])
//                p_t[k][c] = pw[c][k]
__global__ __launch_bounds__(256) void k_transpose(
    const float* __restrict__ qw, const float* __restrict__ kw,
    const float* __restrict__ pw, float* __restrict__ wqk_t,
    float* __restrict__ p_t)
{
    const int i = blockIdx.x * 256 + threadIdx.x;
    if (i < C_DIM * 512) {
        const int k = i >> 9, col = i & 511;
        const int h = col >> 6, j = col & 63;
        wqk_t[i] = (j < 32) ? qw[(size_t)(h * 32 + j) * C_DIM + k]
                            : kw[(size_t)(h * 32 + j - 32) * C_DIM + k];
    } else {
        const int i2 = i - C_DIM * 512;            // < 65536
        const int k = i2 >> 8, c = i2 & 255;
        p_t[i2] = pw[(size_t)c * C_DIM + k];
    }
}

// K1: 2 heads per block. grid (NHEAD/2, N/128, B), block 256.
// Block tile m=128, n=128, BK=32; thread tile 8x8. x double-buffered in LDS
// via global_load_lds; A-fragments read directly from global (wqk_t is 512KB,
// L2-resident; 16 lanes/address -> coalesced broadcast) so the LDS pipe only
// carries the two B-quad b128 reads per k. ONE barrier per chunk.
// 32 global chunks = 4 t x 8 k-chunks.
__global__ __launch_bounds__(256, 4) void k_qk(
    const float* __restrict__ x, const float* __restrict__ wqk,   // [256][512]
    const float* __restrict__ qg, const float* __restrict__ qbeta,
    const float* __restrict__ qmean, const float* __restrict__ qvar,
    const float* __restrict__ kg, const float* __restrict__ kbeta,
    const float* __restrict__ kmean, const float* __restrict__ kvar,
    uint32_t* __restrict__ xbits)
{
    __shared__ float x_lds[2][32 * 128];   // [buf][k][n] 2x16 KB
    __shared__ float inv_lds[128];
    __shared__ float bias_lds[128];
    __shared__ float    qsum_lds[256];     // dedicated epilogue scratch
    __shared__ float    attn_lds[256];
    __shared__ uint32_t pack_lds[256];

    const int tid = threadIdx.x;
    const int hp = blockIdx.x, nt = blockIdx.y, b = blockIdx.z;
    const int n0g = nt * 128;

    const int  mg   = tid >> 4;        // 0..15 -> rows mg*8..+7
    const int  m0   = mg << 3;
    const int  ng   = tid & 15;
    const int  n0   = ng << 2;         // col quad A; quad B = 64+n0
    const int  hsel = mg >> 3;
    const bool is_q = ((mg & 7) < 4);  // wave-uniform

    if (tid < 128) {
        const int m = tid;
        const int hs = m >> 6, j = m & 63;
        const int h = hp * 2 + hs;
        const bool q = (j < 32);
        const float* g  = q ? qg    : kg;
        const float* be = q ? qbeta : kbeta;
        const float* me = q ? qmean : kmean;
        const float* va = q ? qvar  : kvar;
        const int ch = h * DHEAD + (q ? j : j - 32);
        const float iv = __fdiv_rn(g[ch], __fsqrt_rn(__fadd_rn(va[ch], 1e-5f)));
        inv_lds[m]  = iv;
        bias_lds[m] = __fsub_rn(be[ch], __fmul_rn(me[ch], iv));
    }

    // staging: round r covers k-row r*8 + skl, cols scol..+3; dst = r*1024 + tid*4
    const int skl  = tid >> 5;
    const int scol = (tid & 31) << 2;

    float vstate[64];
    #pragma unroll
    for (int i = 0; i < 64; i++) vstate[i] = 0.0f;
    float v_attn = 0.0f;

    // stage chunk 0 into buf 0
    {
        const float* xgp = x + ((size_t)b * C_DIM + skl) * N_DIM + n0g + scol;
        #pragma unroll
        for (int r = 0; r < 4; r++)
            async_copy16(xgp + (size_t)(r * 8) * N_DIM, &x_lds[0][r * 1024 + tid * 4]);
    }

    float acc[64];
    #pragma unroll
    for (int i = 0; i < 64; i++) acc[i] = 0.0f;

    for (int g = 0; g < 32; ++g) {
        const int cur = g & 1;
        __syncthreads();   // drains stage(g) (in flight a full compute phase);
                           // joins readers of buf[1-cur] (chunk g-1)
        if (g + 1 < 32) {  // stage chunk g+1 into the other buffer
            const int g1 = g + 1, tt = g1 >> 3, kk = (g1 & 7) * 32;
            const float* xgp = x + ((size_t)(tt * B_DIM + b) * C_DIM + kk + skl) * N_DIM
                               + n0g + scol;
            float* xd = &x_lds[1 - cur][0];
            #pragma unroll
            for (int r = 0; r < 4; r++)
                async_copy16(xgp + (size_t)(r * 8) * N_DIM, xd + r * 1024 + tid * 4);
        }
        {
            const float* wg = wqk + (size_t)((g & 7) * 32) * 512 + hp * 128 + m0;
            const float* xl = &x_lds[cur][0];
            #pragma unroll 2
            for (int k = 0; k < 32; k++) {
                const float4 a0 = *(const float4*)(wg + (size_t)k * 512);
                const float4 a1 = *(const float4*)(wg + (size_t)k * 512 + 4);
                const float4 b0 = *(const float4*)(xl + k * 128 + n0);
                const float4 b1 = *(const float4*)(xl + k * 128 + 64 + n0);
                FMA_8x8()
            }
        }

        if ((g & 7) == 7) {   // end of one t: BN + LIF + attn + pack epilogue
            const int t = g >> 3;
            #pragma unroll
            for (int r = 0; r < 8; r++) {
                const float iv = inv_lds[m0 + r];
                const float bs = bias_lds[m0 + r];
                #pragma unroll
                for (int j = 0; j < 8; j++) {
                    const float y = __fadd_rn(__fmul_rn(acc[r * 8 + j], iv), bs);
                    acc[r * 8 + j] = lif_step(vstate[r * 8 + j], y, 1.0f);
                }
            }
            qsum_lds[tid] = 0.0f;
            pack_lds[tid] = 0u;
            __syncthreads();
            if (is_q) {
                #pragma unroll
                for (int j = 0; j < 8; j++) {
                    const int col = (j < 4) ? (n0 + j) : (64 + n0 + (j - 4));
                    float cs = acc[j];
                    #pragma unroll
                    for (int r = 1; r < 8; r++) cs += acc[r * 8 + j];
                    atomicAdd(&qsum_lds[hsel * 128 + col], cs);
                }
            }
            __syncthreads();
            attn_lds[tid] = lif_step(v_attn, qsum_lds[tid], 0.5f);
            __syncthreads();
            if (!is_q) {
                #pragma unroll
                for (int r = 0; r < 8; r++) {
                    const int krow = ((mg & 7) - 4) * 8 + r;
                    #pragma unroll
                    for (int ci = 0; ci < 2; ci++) {
                        uint32_t nib = 0;
                        #pragma unroll
                        for (int jj = 0; jj < 4; jj++) {
                            const int col = ci * 64 + n0 + jj;
                            if (acc[r * 8 + ci * 4 + jj] != 0.0f &&
                                attn_lds[hsel * 128 + col] != 0.0f)
                                nib |= (1u << jj);
                        }
                        if (nib) {
                            const int word = ci * 2 + (ng >> 3);
                            const int shf  = (ng & 7) * 4;
                            atomicOr(&pack_lds[hsel * 128 + krow * 4 + word], nib << shf);
                        }
                    }
                }
            }
            __syncthreads();
            {
                const int hs2  = tid >> 7;
                const int rem  = tid & 127;
                const int krow = rem >> 2, word = rem & 3;
                const int ch = (hp * 2 + hs2) * DHEAD + krow;
                xbits[((size_t)(t * B_DIM + b) * C_DIM + ch) * NWRD + nt * 4 + word]
                    = pack_lds[tid];
            }
            // reset acc for next t (registers)
            #pragma unroll
            for (int i = 0; i < 64; i++) acc[i] = 0.0f;
            // next loop-top barrier protects scratch before next epilogue
        }
    }
}

// K2: projection GEMM. grid (C/128, N/128, B), block 256.
// Block tile m=128, n=128, BK=32; thread tile 8x8. x bit-unpacked to LDS
// (double-buffered); A-fragments read directly from global (p_t is 256KB,
// L2-resident). Bits pipelined 2 chunks ahead in a register. ONE barrier per
// chunk; epilogue uses no LDS (no barriers).
__global__ __launch_bounds__(256, 2) void k_proj(
    const uint32_t* __restrict__ xbits, const float* __restrict__ pt,  // [256][256]
    const float* __restrict__ pbias, const float* __restrict__ pg,
    const float* __restrict__ pbeta, const float* __restrict__ pmean,
    const float* __restrict__ pvar, float* __restrict__ out)
{
    __shared__ float x_lds[2][32 * 128];
    __shared__ float inv_lds[128];
    __shared__ float bias_lds[128];
    __shared__ float pb_lds[128];

    const int tid = threadIdx.x;
    const int mt = blockIdx.x, nt = blockIdx.y, b = blockIdx.z;
    const int n0g = nt * 128;
    const int c0  = mt * 128;

    const int mg = tid >> 4, m0 = mg << 3;
    const int ng = tid & 15, n0 = ng << 2;

    if (tid < 128) {
        const int ch = c0 + tid;
        const float iv = __fdiv_rn(pg[ch], __fsqrt_rn(__fadd_rn(pvar[ch], 1e-5f)));
        inv_lds[tid]  = iv;
        bias_lds[tid] = __fsub_rn(pbeta[ch], __fmul_rn(pmean[ch], iv));
        pb_lds[tid]   = pbias[ch];
    }

    // unpack: thread -> chunk k-row urow (0..31), 16 cols at cg*16
    const int urow = tid >> 3, cg = tid & 7;
    const int wsel = nt * 4 + (cg >> 1);
    const int ushf = (cg & 1) * 16;

    float vstate[64];
    #pragma unroll
    for (int i = 0; i < 64; i++) vstate[i] = 0.0f;

    // bits word for global chunk G: xbits[((G>>3)*B+b)*C*NWRD + ((G&7)*32+urow)*NWRD + wsel]
    #define BITS_AT(G) xbits[((size_t)((G) >> 3) * B_DIM + b) * C_DIM * NWRD \
                             + (size_t)(((G) & 7) * 32 + urow) * NWRD + wsel]

    // prologue: unpack chunk 0 into buf0; preload bits(1)
    {
        const uint32_t u0 = BITS_AT(0);
        const uint32_t bits = (u0 >> ushf) & 0xffffu;
        float* xw = &x_lds[0][tid * 16];
        #pragma unroll
        for (int q4 = 0; q4 < 4; q4++) {
            float4 f;
            f.x = ((bits >> (q4 * 4 + 0)) & 1u) ? 1.0f : 0.0f;
            f.y = ((bits >> (q4 * 4 + 1)) & 1u) ? 1.0f : 0.0f;
            f.z = ((bits >> (q4 * 4 + 2)) & 1u) ? 1.0f : 0.0f;
            f.w = ((bits >> (q4 * 4 + 3)) & 1u) ? 1.0f : 0.0f;
            *(float4*)(xw + q4 * 4) = f;
        }
    }
    uint32_t u_a = BITS_AT(1);

    float acc[64];
    #pragma unroll
    for (int i = 0; i < 64; i++) acc[i] = 0.0f;

    for (int g = 0; g < 32; ++g) {
        const int cur = g & 1;
        __syncthreads();   // drains unpack writes for chunk g; joins readers
        if (g + 1 < 32) {  // prepare chunk g+1 in the other buffer
            const uint32_t bits = (u_a >> ushf) & 0xffffu;
            float* xw = &x_lds[1 - cur][tid * 16];
            #pragma unroll
            for (int q4 = 0; q4 < 4; q4++) {
                float4 f;
                f.x = ((bits >> (q4 * 4 + 0)) & 1u) ? 1.0f : 0.0f;
                f.y = ((bits >> (q4 * 4 + 1)) & 1u) ? 1.0f : 0.0f;
                f.z = ((bits >> (q4 * 4 + 2)) & 1u) ? 1.0f : 0.0f;
                f.w = ((bits >> (q4 * 4 + 3)) & 1u) ? 1.0f : 0.0f;
                *(float4*)(xw + q4 * 4) = f;
            }
        }
        if (g + 2 < 32) u_a = BITS_AT(g + 2);   // hidden under compute(g)
        {
            const float* wg = pt + (size_t)((g & 7) * 32) * 256 + c0 + m0;
            const float* xl = &x_lds[cur][0];
            #pragma unroll 2
            for (int k = 0; k < 32; k++) {
                const float4 a0 = *(const float4*)(wg + (size_t)k * 256);
                const float4 a1 = *(const float4*)(wg + (size_t)k * 256 + 4);
                const float4 b0 = *(const float4*)(xl + k * 128 + n0);
                const float4 b1 = *(const float4*)(xl + k * 128 + 64 + n0);
                FMA_8x8()
            }
        }

        if ((g & 7) == 7) {   // end of t: BN + LIF + store (registers + global only)
            const int t = g >> 3;
            #pragma unroll
            for (int r = 0; r < 8; r++) {
                const int ch = c0 + m0 + r;
                const float iv = inv_lds[m0 + r];
                const float bs = bias_lds[m0 + r];
                const float pb = pb_lds[m0 + r];
                float* ob = out + ((size_t)(t * B_DIM + b) * C_DIM + ch) * N_DIM + n0g;
                float oAv[4], oBv[4];
                #pragma unroll
                for (int j = 0; j < 8; j++) {
                    float y = __fadd_rn(acc[r * 8 + j], pb);
                    y = __fadd_rn(__fmul_rn(y, iv), bs);
                    const float s = lif_step(vstate[r * 8 + j], y, 1.0f);
                    if (j < 4) oAv[j] = s; else oBv[j - 4] = s;
                }
                float4 oA, oB;
                oA.x = oAv[0]; oA.y = oAv[1]; oA.z = oAv[2]; oA.w = oAv[3];
                oB.x = oBv[0]; oB.y = oBv[1]; oB.z = oBv[2]; oB.w = oBv[3];
                *(float4*)(ob + n0)      = oA;
                *(float4*)(ob + 64 + n0) = oB;
            }
            #pragma unroll
            for (int i = 0; i < 64; i++) acc[i] = 0.0f;
        }
    }
    #undef BITS_AT
}

extern "C" void kernel_launch(void* const* d_in, const int* in_sizes, int n_in,
                              void* d_out, int out_size, void* d_ws, size_t ws_size,
                              hipStream_t stream) {
    const float* x    = (const float*)d_in[0];
    const float* q_w  = (const float*)d_in[1];
    const float* q_g  = (const float*)d_in[2];
    const float* q_b  = (const float*)d_in[3];
    const float* q_m  = (const float*)d_in[4];
    const float* q_v  = (const float*)d_in[5];
    const float* k_w  = (const float*)d_in[6];
    const float* k_g  = (const float*)d_in[7];
    const float* k_b  = (const float*)d_in[8];
    const float* k_m  = (const float*)d_in[9];
    const float* k_v  = (const float*)d_in[10];
    const float* p_w  = (const float*)d_in[11];
    const float* p_b  = (const float*)d_in[12];
    const float* p_g  = (const float*)d_in[13];
    const float* p_be = (const float*)d_in[14];
    const float* p_m  = (const float*)d_in[15];
    const float* p_v  = (const float*)d_in[16];

    // ws layout: wqk_t 512KB | p_t 256KB | xbits 4MB
    float*    wqk_t = (float*)d_ws;
    float*    p_t   = (float*)((char*)d_ws + 524288);
    uint32_t* xbits = (uint32_t*)((char*)d_ws + 786432);
    float*    out   = (float*)d_out;

    k_transpose<<<768, 256, 0, stream>>>(q_w, k_w, p_w, wqk_t, p_t);

    dim3 g1(NHEAD / 2, N_DIM / 128, B_DIM);
    k_qk<<<g1, 256, 0, stream>>>(x, wqk_t, q_g, q_b, q_m, q_v,
                                 k_g, k_b, k_m, k_v, xbits);

    dim3 g2(C_DIM / 128, N_DIM / 128, B_DIM);
    k_proj<<<g2, 256, 0, stream>>>(xbits, p_t, p_b, p_g, p_be, p_m, p_v, out);
}

// Round 4
// 952.154 us; speedup vs baseline: 2.9935x; 1.0450x over previous
//
#include <hip/hip_runtime.h>
#include <cstdint>
#include <cstddef>

#define T_DIM 4
#define B_DIM 32
#define C_DIM 256
#define N_DIM 1024
#define NHEAD 8
#define DHEAD 32
#define NWRD 32   // N/32 bit-words per row

// LIF step, exact reference rounding: v += (x-v)/2; s = v>=vth; hard reset.
__device__ __forceinline__ float lif_step(float& v, float x, float vth) {
    v = __fadd_rn(v, __fmul_rn(__fsub_rn(x, v), 0.5f));
    const float s = (v >= vth) ? 1.0f : 0.0f;
    if (s != 0.0f) v = 0.0f;
    return s;
}

// async global->LDS, 16B per lane. LDS dest = wave-uniform base + lane*16.
__device__ __forceinline__ void async_copy16(const float* g, float* l) {
    __builtin_amdgcn_global_load_lds(
        (const __attribute__((address_space(1))) unsigned int*)g,
        (__attribute__((address_space(3))) unsigned int*)l, 16, 0, 0);
}

// one a-element times 8 cols (two float4 col-quads), strict k-ascending chains
#define FMA_ROW(r, av)                                \
    acc[(r)*8+0] = fmaf(av, b0.x, acc[(r)*8+0]);      \
    acc[(r)*8+1] = fmaf(av, b0.y, acc[(r)*8+1]);      \
    acc[(r)*8+2] = fmaf(av, b0.z, acc[(r)*8+2]);      \
    acc[(r)*8+3] = fmaf(av, b0.w, acc[(r)*8+3]);      \
    acc[(r)*8+4] = fmaf(av, b1.x, acc[(r)*8+4]);      \
    acc[(r)*8+5] = fmaf(av, b1.y, acc[(r)*8+5]);      \
    acc[(r)*8+6] = fmaf(av, b1.z, acc[(r)*8+6]);      \
    acc[(r)*8+7] = fmaf(av, b1.w, acc[(r)*8+7]);

#define FMA_8x8()        \
    FMA_ROW(0, a0.x)     \
    FMA_ROW(1, a0.y)     \
    FMA_ROW(2, a0.z)     \
    FMA_ROW(3, a0.w)     \
    FMA_ROW(4, a1.x)     \
    FMA_ROW(5, a1.y)     \
    FMA_ROW(6, a1.z)     \
    FMA_ROW(7, a1.w)

// Pre-transpose: wqk_t[k][h*64+j] = (j<32 ? qw[h*32+j][k] : kw[h*32+j-32][k])
//                p_t[k][c] = pw[c][k]
__global__ __launch_bounds__(256) void k_transpose(
    const float* __restrict__ qw, const float* __restrict__ kw,
    const float* __restrict__ pw, float* __restrict__ wqk_t,
    float* __restrict__ p_t)
{
    const int i = blockIdx.x * 256 + threadIdx.x;
    if (i < C_DIM * 512) {
        const int k = i >> 9, col = i & 511;
        const int h = col >> 6, j = col & 63;
        wqk_t[i] = (j < 32) ? qw[(size_t)(h * 32 + j) * C_DIM + k]
                            : kw[(size_t)(h * 32 + j - 32) * C_DIM + k];
    } else {
        const int i2 = i - C_DIM * 512;            // < 65536
        const int k = i2 >> 8, c = i2 & 255;
        p_t[i2] = pw[(size_t)c * C_DIM + k];
    }
}

// K1: 2 heads per block. grid (NHEAD/2, N/128, B), block 256.
// Block tile m=128, n=128, BK=32; thread tile 8x8. x double-buffered in LDS
// via global_load_lds; A-fragments read directly from global (wqk_t is 512KB,
// L2-resident; 16 lanes/address -> coalesced broadcast) so the LDS pipe only
// carries the two B-quad b128 reads per k. ONE barrier per chunk.
// launch_bounds (256,2): do NOT clamp VGPRs (acc[64] must stay in registers;
// (256,4) forced VGPR=64 -> inner-loop spill, 245MB scratch writes in round 3).
// LDS 36.9KB still admits 4 blocks/CU when the allocator lands <=128 VGPR.
__global__ __launch_bounds__(256, 2) void k_qk(
    const float* __restrict__ x, const float* __restrict__ wqk,   // [256][512]
    const float* __restrict__ qg, const float* __restrict__ qbeta,
    const float* __restrict__ qmean, const float* __restrict__ qvar,
    const float* __restrict__ kg, const float* __restrict__ kbeta,
    const float* __restrict__ kmean, const float* __restrict__ kvar,
    uint32_t* __restrict__ xbits)
{
    __shared__ float x_lds[2][32 * 128];   // [buf][k][n] 2x16 KB
    __shared__ float inv_lds[128];
    __shared__ float bias_lds[128];
    __shared__ float    qsum_lds[256];     // dedicated epilogue scratch
    __shared__ float    attn_lds[256];
    __shared__ uint32_t pack_lds[256];

    const int tid = threadIdx.x;
    const int hp = blockIdx.x, nt = blockIdx.y, b = blockIdx.z;
    const int n0g = nt * 128;

    const int  mg   = tid >> 4;        // 0..15 -> rows mg*8..+7
    const int  m0   = mg << 3;
    const int  ng   = tid & 15;
    const int  n0   = ng << 2;         // col quad A; quad B = 64+n0
    const int  hsel = mg >> 3;
    const bool is_q = ((mg & 7) < 4);  // wave-uniform

    if (tid < 128) {
        const int m = tid;
        const int hs = m >> 6, j = m & 63;
        const int h = hp * 2 + hs;
        const bool q = (j < 32);
        const float* g  = q ? qg    : kg;
        const float* be = q ? qbeta : kbeta;
        const float* me = q ? qmean : kmean;
        const float* va = q ? qvar  : kvar;
        const int ch = h * DHEAD + (q ? j : j - 32);
        const float iv = __fdiv_rn(g[ch], __fsqrt_rn(__fadd_rn(va[ch], 1e-5f)));
        inv_lds[m]  = iv;
        bias_lds[m] = __fsub_rn(be[ch], __fmul_rn(me[ch], iv));
    }

    // staging: round r covers k-row r*8 + skl, cols scol..+3; dst = r*1024 + tid*4
    const int skl  = tid >> 5;
    const int scol = (tid & 31) << 2;

    float vstate[64];
    #pragma unroll
    for (int i = 0; i < 64; i++) vstate[i] = 0.0f;
    float v_attn = 0.0f;

    // stage chunk 0 into buf 0
    {
        const float* xgp = x + ((size_t)b * C_DIM + skl) * N_DIM + n0g + scol;
        #pragma unroll
        for (int r = 0; r < 4; r++)
            async_copy16(xgp + (size_t)(r * 8) * N_DIM, &x_lds[0][r * 1024 + tid * 4]);
    }

    float acc[64];
    #pragma unroll
    for (int i = 0; i < 64; i++) acc[i] = 0.0f;

    for (int g = 0; g < 32; ++g) {
        const int cur = g & 1;
        __syncthreads();   // drains stage(g) (in flight a full compute phase);
                           // joins readers of buf[1-cur] (chunk g-1)
        if (g + 1 < 32) {  // stage chunk g+1 into the other buffer
            const int g1 = g + 1, tt = g1 >> 3, kk = (g1 & 7) * 32;
            const float* xgp = x + ((size_t)(tt * B_DIM + b) * C_DIM + kk + skl) * N_DIM
                               + n0g + scol;
            float* xd = &x_lds[1 - cur][0];
            #pragma unroll
            for (int r = 0; r < 4; r++)
                async_copy16(xgp + (size_t)(r * 8) * N_DIM, xd + r * 1024 + tid * 4);
        }
        {
            const float* wg = wqk + (size_t)((g & 7) * 32) * 512 + hp * 128 + m0;
            const float* xl = &x_lds[cur][0];
            #pragma unroll 2
            for (int k = 0; k < 32; k++) {
                const float4 a0 = *(const float4*)(wg + (size_t)k * 512);
                const float4 a1 = *(const float4*)(wg + (size_t)k * 512 + 4);
                const float4 b0 = *(const float4*)(xl + k * 128 + n0);
                const float4 b1 = *(const float4*)(xl + k * 128 + 64 + n0);
                FMA_8x8()
            }
        }

        if ((g & 7) == 7) {   // end of one t: BN + LIF + attn + pack epilogue
            const int t = g >> 3;
            #pragma unroll
            for (int r = 0; r < 8; r++) {
                const float iv = inv_lds[m0 + r];
                const float bs = bias_lds[m0 + r];
                #pragma unroll
                for (int j = 0; j < 8; j++) {
                    const float y = __fadd_rn(__fmul_rn(acc[r * 8 + j], iv), bs);
                    acc[r * 8 + j] = lif_step(vstate[r * 8 + j], y, 1.0f);
                }
            }
            qsum_lds[tid] = 0.0f;
            pack_lds[tid] = 0u;
            __syncthreads();
            if (is_q) {
                #pragma unroll
                for (int j = 0; j < 8; j++) {
                    const int col = (j < 4) ? (n0 + j) : (64 + n0 + (j - 4));
                    float cs = acc[j];
                    #pragma unroll
                    for (int r = 1; r < 8; r++) cs += acc[r * 8 + j];
                    atomicAdd(&qsum_lds[hsel * 128 + col], cs);
                }
            }
            __syncthreads();
            attn_lds[tid] = lif_step(v_attn, qsum_lds[tid], 0.5f);
            __syncthreads();
            if (!is_q) {
                #pragma unroll
                for (int r = 0; r < 8; r++) {
                    const int krow = ((mg & 7) - 4) * 8 + r;
                    #pragma unroll
                    for (int ci = 0; ci < 2; ci++) {
                        uint32_t nib = 0;
                        #pragma unroll
                        for (int jj = 0; jj < 4; jj++) {
                            const int col = ci * 64 + n0 + jj;
                            if (acc[r * 8 + ci * 4 + jj] != 0.0f &&
                                attn_lds[hsel * 128 + col] != 0.0f)
                                nib |= (1u << jj);
                        }
                        if (nib) {
                            const int word = ci * 2 + (ng >> 3);
                            const int shf  = (ng & 7) * 4;
                            atomicOr(&pack_lds[hsel * 128 + krow * 4 + word], nib << shf);
                        }
                    }
                }
            }
            __syncthreads();
            {
                const int hs2  = tid >> 7;
                const int rem  = tid & 127;
                const int krow = rem >> 2, word = rem & 3;
                const int ch = (hp * 2 + hs2) * DHEAD + krow;
                xbits[((size_t)(t * B_DIM + b) * C_DIM + ch) * NWRD + nt * 4 + word]
                    = pack_lds[tid];
            }
            // reset acc for next t (registers)
            #pragma unroll
            for (int i = 0; i < 64; i++) acc[i] = 0.0f;
            // next loop-top barrier protects scratch before next epilogue
        }
    }
}

// K2: projection GEMM. grid (C/128, N/128, B), block 256.
// Block tile m=128, n=128, BK=32; thread tile 8x8. x bit-unpacked to LDS
// (double-buffered); A-fragments read directly from global (p_t is 256KB,
// L2-resident). Bits pipelined 2 chunks ahead in a register. ONE barrier per
// chunk; epilogue uses no LDS (no barriers).
__global__ __launch_bounds__(256, 2) void k_proj(
    const uint32_t* __restrict__ xbits, const float* __restrict__ pt,  // [256][256]
    const float* __restrict__ pbias, const float* __restrict__ pg,
    const float* __restrict__ pbeta, const float* __restrict__ pmean,
    const float* __restrict__ pvar, float* __restrict__ out)
{
    __shared__ float x_lds[2][32 * 128];
    __shared__ float inv_lds[128];
    __shared__ float bias_lds[128];
    __shared__ float pb_lds[128];

    const int tid = threadIdx.x;
    const int mt = blockIdx.x, nt = blockIdx.y, b = blockIdx.z;
    const int n0g = nt * 128;
    const int c0  = mt * 128;

    const int mg = tid >> 4, m0 = mg << 3;
    const int ng = tid & 15, n0 = ng << 2;

    if (tid < 128) {
        const int ch = c0 + tid;
        const float iv = __fdiv_rn(pg[ch], __fsqrt_rn(__fadd_rn(pvar[ch], 1e-5f)));
        inv_lds[tid]  = iv;
        bias_lds[tid] = __fsub_rn(pbeta[ch], __fmul_rn(pmean[ch], iv));
        pb_lds[tid]   = pbias[ch];
    }

    // unpack: thread -> chunk k-row urow (0..31), 16 cols at cg*16
    const int urow = tid >> 3, cg = tid & 7;
    const int wsel = nt * 4 + (cg >> 1);
    const int ushf = (cg & 1) * 16;

    float vstate[64];
    #pragma unroll
    for (int i = 0; i < 64; i++) vstate[i] = 0.0f;

    // bits word for global chunk G: xbits[((G>>3)*B+b)*C*NWRD + ((G&7)*32+urow)*NWRD + wsel]
    #define BITS_AT(G) xbits[((size_t)((G) >> 3) * B_DIM + b) * C_DIM * NWRD \
                             + (size_t)(((G) & 7) * 32 + urow) * NWRD + wsel]

    // prologue: unpack chunk 0 into buf0; preload bits(1)
    {
        const uint32_t u0 = BITS_AT(0);
        const uint32_t bits = (u0 >> ushf) & 0xffffu;
        float* xw = &x_lds[0][tid * 16];
        #pragma unroll
        for (int q4 = 0; q4 < 4; q4++) {
            float4 f;
            f.x = ((bits >> (q4 * 4 + 0)) & 1u) ? 1.0f : 0.0f;
            f.y = ((bits >> (q4 * 4 + 1)) & 1u) ? 1.0f : 0.0f;
            f.z = ((bits >> (q4 * 4 + 2)) & 1u) ? 1.0f : 0.0f;
            f.w = ((bits >> (q4 * 4 + 3)) & 1u) ? 1.0f : 0.0f;
            *(float4*)(xw + q4 * 4) = f;
        }
    }
    uint32_t u_a = BITS_AT(1);

    float acc[64];
    #pragma unroll
    for (int i = 0; i < 64; i++) acc[i] = 0.0f;

    for (int g = 0; g < 32; ++g) {
        const int cur = g & 1;
        __syncthreads();   // drains unpack writes for chunk g; joins readers
        if (g + 1 < 32) {  // prepare chunk g+1 in the other buffer
            const uint32_t bits = (u_a >> ushf) & 0xffffu;
            float* xw = &x_lds[1 - cur][tid * 16];
            #pragma unroll
            for (int q4 = 0; q4 < 4; q4++) {
                float4 f;
                f.x = ((bits >> (q4 * 4 + 0)) & 1u) ? 1.0f : 0.0f;
                f.y = ((bits >> (q4 * 4 + 1)) & 1u) ? 1.0f : 0.0f;
                f.z = ((bits >> (q4 * 4 + 2)) & 1u) ? 1.0f : 0.0f;
                f.w = ((bits >> (q4 * 4 + 3)) & 1u) ? 1.0f : 0.0f;
                *(float4*)(xw + q4 * 4) = f;
            }
        }
        if (g + 2 < 32) u_a = BITS_AT(g + 2);   // hidden under compute(g)
        {
            const float* wg = pt + (size_t)((g & 7) * 32) * 256 + c0 + m0;
            const float* xl = &x_lds[cur][0];
            #pragma unroll 2
            for (int k = 0; k < 32; k++) {
                const float4 a0 = *(const float4*)(wg + (size_t)k * 256);
                const float4 a1 = *(const float4*)(wg + (size_t)k * 256 + 4);
                const float4 b0 = *(const float4*)(xl + k * 128 + n0);
                const float4 b1 = *(const float4*)(xl + k * 128 + 64 + n0);
                FMA_8x8()
            }
        }

        if ((g & 7) == 7) {   // end of t: BN + LIF + store (registers + global only)
            const int t = g >> 3;
            #pragma unroll
            for (int r = 0; r < 8; r++) {
                const int ch = c0 + m0 + r;
                const float iv = inv_lds[m0 + r];
                const float bs = bias_lds[m0 + r];
                const float pb = pb_lds[m0 + r];
                float* ob = out + ((size_t)(t * B_DIM + b) * C_DIM + ch) * N_DIM + n0g;
                float oAv[4], oBv[4];
                #pragma unroll
                for (int j = 0; j < 8; j++) {
                    float y = __fadd_rn(acc[r * 8 + j], pb);
                    y = __fadd_rn(__fmul_rn(y, iv), bs);
                    const float s = lif_step(vstate[r * 8 + j], y, 1.0f);
                    if (j < 4) oAv[j] = s; else oBv[j - 4] = s;
                }
                float4 oA, oB;
                oA.x = oAv[0]; oA.y = oAv[1]; oA.z = oAv[2]; oA.w = oAv[3];
                oB.x = oBv[0]; oB.y = oBv[1]; oB.z = oBv[2]; oB.w = oBv[3];
                *(float4*)(ob + n0)      = oA;
                *(float4*)(ob + 64 + n0) = oB;
            }
            #pragma unroll
            for (int i = 0; i < 64; i++) acc[i] = 0.0f;
        }
    }
    #undef BITS_AT
}

extern "C" void kernel_launch(void* const* d_in, const int* in_sizes, int n_in,
                              void* d_out, int out_size, void* d_ws, size_t ws_size,
                              hipStream_t stream) {
    const float* x    = (const float*)d_in[0];
    const float* q_w  = (const float*)d_in[1];
    const float* q_g  = (const float*)d_in[2];
    const float* q_b  = (const float*)d_in[3];
    const float* q_m  = (const float*)d_in[4];
    const float* q_v  = (const float*)d_in[5];
    const float* k_w  = (const float*)d_in[6];
    const float* k_g  = (const float*)d_in[7];
    const float* k_b  = (const float*)d_in[8];
    const float* k_m  = (const float*)d_in[9];
    const float* k_v  = (const float*)d_in[10];
    const float* p_w  = (const float*)d_in[11];
    const float* p_b  = (const float*)d_in[12];
    const float* p_g  = (const float*)d_in[13];
    const float* p_be = (const float*)d_in[14];
    const float* p_m  = (const float*)d_in[15];
    const float* p_v  = (const float*)d_in[16];

    // ws layout: wqk_t 512KB | p_t 256KB | xbits 4MB
    float*    wqk_t = (float*)d_ws;
    float*    p_t   = (float*)((char*)d_ws + 524288);
    uint32_t* xbits = (uint32_t*)((char*)d_ws + 786432);
    float*    out   = (float*)d_out;

    k_transpose<<<768, 256, 0, stream>>>(q_w, k_w, p_w, wqk_t, p_t);

    dim3 g1(NHEAD / 2, N_DIM / 128, B_DIM);
    k_qk<<<g1, 256, 0, stream>>>(x, wqk_t, q_g, q_b, q_m, q_v,
                                 k_g, k_b, k_m, k_v, xbits);

    dim3 g2(C_DIM / 128, N_DIM / 128, B_DIM);
    k_proj<<<g2, 256, 0, stream>>>(xbits, p_t, p_b, p_g, p_be, p_m, p_v, out);
}

// Round 5
// 846.882 us; speedup vs baseline: 3.3656x; 1.1243x over previous
//
#include <hip/hip_runtime.h>
#include <cstdint>
#include <cstddef>

#define T_DIM 4
#define B_DIM 32
#define C_DIM 256
#define N_DIM 1024
#define NHEAD 8
#define DHEAD 32
#define NWRD 32   // N/32 bit-words per row

// LIF step, exact reference rounding: v += (x-v)/2; s = v>=vth; hard reset.
__device__ __forceinline__ float lif_step(float& v, float x, float vth) {
    v = __fadd_rn(v, __fmul_rn(__fsub_rn(x, v), 0.5f));
    const float s = (v >= vth) ? 1.0f : 0.0f;
    if (s != 0.0f) v = 0.0f;
    return s;
}

// async global->LDS, 16B per lane. LDS dest = wave-uniform base + lane*16.
__device__ __forceinline__ void async_copy16(const float* g, float* l) {
    __builtin_amdgcn_global_load_lds(
        (const __attribute__((address_space(1))) unsigned int*)g,
        (__attribute__((address_space(3))) unsigned int*)l, 16, 0, 0);
}

// one a-element times 4 cols, strict k-ascending chains per acc element
#define FMA_ROW4(r, av)                               \
    acc[(r)*4+0] = fmaf(av, b0.x, acc[(r)*4+0]);      \
    acc[(r)*4+1] = fmaf(av, b0.y, acc[(r)*4+1]);      \
    acc[(r)*4+2] = fmaf(av, b0.z, acc[(r)*4+2]);      \
    acc[(r)*4+3] = fmaf(av, b0.w, acc[(r)*4+3]);

#define FMA_8x4()        \
    FMA_ROW4(0, a0.x)    \
    FMA_ROW4(1, a0.y)    \
    FMA_ROW4(2, a0.z)    \
    FMA_ROW4(3, a0.w)    \
    FMA_ROW4(4, a1.x)    \
    FMA_ROW4(5, a1.y)    \
    FMA_ROW4(6, a1.z)    \
    FMA_ROW4(7, a1.w)

// Pre-transpose: wqk_t[k][h*64+j] = (j<32 ? qw[h*32+j][k] : kw[h*32+j-32][k])
//                p_t[k][c] = pw[c][k]
__global__ __launch_bounds__(256) void k_transpose(
    const float* __restrict__ qw, const float* __restrict__ kw,
    const float* __restrict__ pw, float* __restrict__ wqk_t,
    float* __restrict__ p_t)
{
    const int i = blockIdx.x * 256 + threadIdx.x;
    if (i < C_DIM * 512) {
        const int k = i >> 9, col = i & 511;
        const int h = col >> 6, j = col & 63;
        wqk_t[i] = (j < 32) ? qw[(size_t)(h * 32 + j) * C_DIM + k]
                            : kw[(size_t)(h * 32 + j - 32) * C_DIM + k];
    } else {
        const int i2 = i - C_DIM * 512;            // < 65536
        const int k = i2 >> 8, c = i2 & 255;
        p_t[i2] = pw[(size_t)c * C_DIM + k];
    }
}

// K1: 2 heads per block. grid (NHEAD/2, N/128, B), block 512.
// Block tile m=128, n=128, BK=32; thread tile 8x4 (acc 32 + vstate 32 regs ->
// total regs ~105 < 128 -> 4 waves/SIMD; with 69.6KB LDS -> 2 blocks x 8
// waves = 16 waves/CU, 2x the 8x8/256-thread variant whose acc+vstate=128
// pushed unified VGPR+AGPR use to ~170 -> 2 waves/SIMD). Both operands in
// LDS, double-buffered via global_load_lds; ONE barrier per chunk.
// 32 global chunks = 4 t x 8 k-chunks.
__global__ __launch_bounds__(512, 4) void k_qk(
    const float* __restrict__ x, const float* __restrict__ wqk,   // [256][512]
    const float* __restrict__ qg, const float* __restrict__ qbeta,
    const float* __restrict__ qmean, const float* __restrict__ qvar,
    const float* __restrict__ kg, const float* __restrict__ kbeta,
    const float* __restrict__ kmean, const float* __restrict__ kvar,
    uint32_t* __restrict__ xbits)
{
    __shared__ float w_lds[2][32 * 128];   // [buf][k][m] 2x16 KB
    __shared__ float x_lds[2][32 * 128];   // [buf][k][n] 2x16 KB
    __shared__ float inv_lds[128];
    __shared__ float bias_lds[128];
    __shared__ float    qsum_lds[256];     // dedicated epilogue scratch
    __shared__ float    attn_lds[256];
    __shared__ uint32_t pack_lds[256];

    const int tid = threadIdx.x;
    const int hp = blockIdx.x, nt = blockIdx.y, b = blockIdx.z;
    const int n0g = nt * 128;

    const int  mg   = tid >> 5;        // 0..15 -> rows mg*8..+7
    const int  m0   = mg << 3;
    const int  ng   = tid & 31;
    const int  n0   = ng << 2;         // cols n0..n0+3
    const int  hsel = mg >> 3;
    const bool is_q = ((mg & 7) < 4);  // wave-uniform (mg pairs per wave)

    if (tid < 128) {
        const int m = tid;
        const int hs = m >> 6, j = m & 63;
        const int h = hp * 2 + hs;
        const bool q = (j < 32);
        const float* g  = q ? qg    : kg;
        const float* be = q ? qbeta : kbeta;
        const float* me = q ? qmean : kmean;
        const float* va = q ? qvar  : kvar;
        const int ch = h * DHEAD + (q ? j : j - 32);
        const float iv = __fdiv_rn(g[ch], __fsqrt_rn(__fadd_rn(va[ch], 1e-5f)));
        inv_lds[m]  = iv;
        bias_lds[m] = __fsub_rn(be[ch], __fmul_rn(me[ch], iv));
    }

    // staging: round r covers k-row r*16 + skl, cols scol..+3; dst = r*2048 + tid*4
    const int skl  = tid >> 5;         // 0..15
    const int scol = (tid & 31) << 2;
    const float* wgp = wqk + (size_t)skl * 512 + hp * 128 + scol;

    float vstate[32];
    #pragma unroll
    for (int i = 0; i < 32; i++) vstate[i] = 0.0f;
    float v_attn = 0.0f;

    // stage chunk 0 into buf 0
    {
        const float* xgp = x + ((size_t)b * C_DIM + skl) * N_DIM + n0g + scol;
        #pragma unroll
        for (int r = 0; r < 2; r++) {
            async_copy16(wgp + (size_t)(r * 16) * 512,  &w_lds[0][r * 2048 + tid * 4]);
            async_copy16(xgp + (size_t)(r * 16) * N_DIM, &x_lds[0][r * 2048 + tid * 4]);
        }
    }

    float acc[32];
    #pragma unroll
    for (int i = 0; i < 32; i++) acc[i] = 0.0f;

    for (int g = 0; g < 32; ++g) {
        const int cur = g & 1;
        __syncthreads();   // drains stage(g) (in flight a full compute phase);
                           // joins readers of buf[1-cur] (chunk g-1)
        if (g + 1 < 32) {  // stage chunk g+1 into the other buffer
            const int g1 = g + 1, tt = g1 >> 3, kk = (g1 & 7) * 32;
            const float* xgp = x + ((size_t)(tt * B_DIM + b) * C_DIM + kk + skl) * N_DIM
                               + n0g + scol;
            float* wd = &w_lds[1 - cur][0];
            float* xd = &x_lds[1 - cur][0];
            #pragma unroll
            for (int r = 0; r < 2; r++) {
                async_copy16(wgp + (size_t)(kk + r * 16) * 512,  wd + r * 2048 + tid * 4);
                async_copy16(xgp + (size_t)(r * 16) * N_DIM,     xd + r * 2048 + tid * 4);
            }
        }
        {
            const float* wl = &w_lds[cur][0];
            const float* xl = &x_lds[cur][0];
            #pragma unroll 2
            for (int k = 0; k < 32; k++) {
                const float4 a0 = *(const float4*)(wl + k * 128 + m0);
                const float4 a1 = *(const float4*)(wl + k * 128 + m0 + 4);
                const float4 b0 = *(const float4*)(xl + k * 128 + n0);
                FMA_8x4()
            }
        }

        if ((g & 7) == 7) {   // end of one t: BN + LIF + attn + pack epilogue
            const int t = g >> 3;
            #pragma unroll
            for (int r = 0; r < 8; r++) {
                const float iv = inv_lds[m0 + r];
                const float bs = bias_lds[m0 + r];
                #pragma unroll
                for (int j = 0; j < 4; j++) {
                    const float y = __fadd_rn(__fmul_rn(acc[r * 4 + j], iv), bs);
                    acc[r * 4 + j] = lif_step(vstate[r * 4 + j], y, 1.0f);
                }
            }
            if (tid < 256) { qsum_lds[tid] = 0.0f; pack_lds[tid] = 0u; }
            __syncthreads();
            if (is_q) {
                #pragma unroll
                for (int j = 0; j < 4; j++) {
                    const int col = n0 + j;
                    float cs = acc[j];
                    #pragma unroll
                    for (int r = 1; r < 8; r++) cs += acc[r * 4 + j];
                    atomicAdd(&qsum_lds[hsel * 128 + col], cs);
                }
            }
            __syncthreads();
            if (tid < 256) attn_lds[tid] = lif_step(v_attn, qsum_lds[tid], 0.5f);
            __syncthreads();
            if (!is_q) {
                #pragma unroll
                for (int r = 0; r < 8; r++) {
                    const int krow = ((mg & 7) - 4) * 8 + r;
                    uint32_t nib = 0;
                    #pragma unroll
                    for (int jj = 0; jj < 4; jj++) {
                        if (acc[r * 4 + jj] != 0.0f &&
                            attn_lds[hsel * 128 + n0 + jj] != 0.0f)
                            nib |= (1u << jj);
                    }
                    if (nib) {
                        const int word = ng >> 3;
                        const int shf  = (ng & 7) * 4;
                        atomicOr(&pack_lds[hsel * 128 + krow * 4 + word], nib << shf);
                    }
                }
            }
            __syncthreads();
            if (tid < 256) {
                const int hs2  = tid >> 7;
                const int rem  = tid & 127;
                const int krow = rem >> 2, word = rem & 3;
                const int ch = (hp * 2 + hs2) * DHEAD + krow;
                xbits[((size_t)(t * B_DIM + b) * C_DIM + ch) * NWRD + nt * 4 + word]
                    = pack_lds[tid];
            }
            // reset acc for next t (registers)
            #pragma unroll
            for (int i = 0; i < 32; i++) acc[i] = 0.0f;
            // next loop-top barrier protects scratch before next epilogue
        }
    }
}

// K2: projection GEMM. grid (C/128, N/128, B), block 512.
// Block tile m=128, n=128, BK=32; thread tile 8x4. Double-buffered w (async)
// + x (bit-unpack to LDS, 8 floats/thread); bits pipelined 2 chunks ahead.
// ONE barrier per chunk; epilogue uses no LDS (no barriers).
__global__ __launch_bounds__(512, 4) void k_proj(
    const uint32_t* __restrict__ xbits, const float* __restrict__ pt,  // [256][256]
    const float* __restrict__ pbias, const float* __restrict__ pg,
    const float* __restrict__ pbeta, const float* __restrict__ pmean,
    const float* __restrict__ pvar, float* __restrict__ out)
{
    __shared__ float w_lds[2][32 * 128];
    __shared__ float x_lds[2][32 * 128];
    __shared__ float inv_lds[128];
    __shared__ float bias_lds[128];
    __shared__ float pb_lds[128];

    const int tid = threadIdx.x;
    const int mt = blockIdx.x, nt = blockIdx.y, b = blockIdx.z;
    const int n0g = nt * 128;
    const int c0  = mt * 128;

    const int mg = tid >> 5, m0 = mg << 3;
    const int ng = tid & 31, n0 = ng << 2;

    if (tid < 128) {
        const int ch = c0 + tid;
        const float iv = __fdiv_rn(pg[ch], __fsqrt_rn(__fadd_rn(pvar[ch], 1e-5f)));
        inv_lds[tid]  = iv;
        bias_lds[tid] = __fsub_rn(pbeta[ch], __fmul_rn(pmean[ch], iv));
        pb_lds[tid]   = pbias[ch];
    }

    const int skl  = tid >> 5;
    const int scol = (tid & 31) << 2;
    const float* wgp = pt + (size_t)skl * 256 + c0 + scol;

    // unpack: thread -> chunk k-row urow (0..31), 8 cols at cg*8
    const int urow = tid >> 4, cg = tid & 15;
    const int wsel = nt * 4 + (cg >> 2);
    const int ushf = (cg & 3) * 8;

    float vstate[32];
    #pragma unroll
    for (int i = 0; i < 32; i++) vstate[i] = 0.0f;

    // bits word for global chunk G: xbits[((G>>3)*B+b)*C*NWRD + ((G&7)*32+urow)*NWRD + wsel]
    #define BITS_AT(G) xbits[((size_t)((G) >> 3) * B_DIM + b) * C_DIM * NWRD \
                             + (size_t)(((G) & 7) * 32 + urow) * NWRD + wsel]

    // prologue: unpack chunk 0 + stage w(0) into buf0; preload bits(1)
    {
        const uint32_t u0 = BITS_AT(0);
        const uint32_t bits = (u0 >> ushf) & 0xffu;
        float* xw = &x_lds[0][urow * 128 + cg * 8];
        float4 f0, f1;
        f0.x = ((bits >> 0) & 1u) ? 1.0f : 0.0f;
        f0.y = ((bits >> 1) & 1u) ? 1.0f : 0.0f;
        f0.z = ((bits >> 2) & 1u) ? 1.0f : 0.0f;
        f0.w = ((bits >> 3) & 1u) ? 1.0f : 0.0f;
        f1.x = ((bits >> 4) & 1u) ? 1.0f : 0.0f;
        f1.y = ((bits >> 5) & 1u) ? 1.0f : 0.0f;
        f1.z = ((bits >> 6) & 1u) ? 1.0f : 0.0f;
        f1.w = ((bits >> 7) & 1u) ? 1.0f : 0.0f;
        *(float4*)(xw)     = f0;
        *(float4*)(xw + 4) = f1;
        #pragma unroll
        for (int r = 0; r < 2; r++)
            async_copy16(wgp + (size_t)(r * 16) * 256, &w_lds[0][r * 2048 + tid * 4]);
    }
    uint32_t u_a = BITS_AT(1);

    float acc[32];
    #pragma unroll
    for (int i = 0; i < 32; i++) acc[i] = 0.0f;

    for (int g = 0; g < 32; ++g) {
        const int cur = g & 1;
        __syncthreads();   // drains unpack writes + w copies for chunk g;
                           // joins readers of buf[1-cur]
        if (g + 1 < 32) {  // prepare chunk g+1 in the other buffer
            const int kk = ((g + 1) & 7) * 32;
            const uint32_t bits = (u_a >> ushf) & 0xffu;
            float* xw = &x_lds[1 - cur][urow * 128 + cg * 8];
            float4 f0, f1;
            f0.x = ((bits >> 0) & 1u) ? 1.0f : 0.0f;
            f0.y = ((bits >> 1) & 1u) ? 1.0f : 0.0f;
            f0.z = ((bits >> 2) & 1u) ? 1.0f : 0.0f;
            f0.w = ((bits >> 3) & 1u) ? 1.0f : 0.0f;
            f1.x = ((bits >> 4) & 1u) ? 1.0f : 0.0f;
            f1.y = ((bits >> 5) & 1u) ? 1.0f : 0.0f;
            f1.z = ((bits >> 6) & 1u) ? 1.0f : 0.0f;
            f1.w = ((bits >> 7) & 1u) ? 1.0f : 0.0f;
            *(float4*)(xw)     = f0;
            *(float4*)(xw + 4) = f1;
            float* wd = &w_lds[1 - cur][0];
            #pragma unroll
            for (int r = 0; r < 2; r++)
                async_copy16(wgp + (size_t)(kk + r * 16) * 256, wd + r * 2048 + tid * 4);
        }
        if (g + 2 < 32) u_a = BITS_AT(g + 2);   // hidden under compute(g)
        {
            const float* wl = &w_lds[cur][0];
            const float* xl = &x_lds[cur][0];
            #pragma unroll 2
            for (int k = 0; k < 32; k++) {
                const float4 a0 = *(const float4*)(wl + k * 128 + m0);
                const float4 a1 = *(const float4*)(wl + k * 128 + m0 + 4);
                const float4 b0 = *(const float4*)(xl + k * 128 + n0);
                FMA_8x4()
            }
        }

        if ((g & 7) == 7) {   // end of t: bias + BN + LIF + store (regs + global)
            const int t = g >> 3;
            #pragma unroll
            for (int r = 0; r < 8; r++) {
                const int ch = c0 + m0 + r;
                const float iv = inv_lds[m0 + r];
                const float bs = bias_lds[m0 + r];
                const float pb = pb_lds[m0 + r];
                float* ob = out + ((size_t)(t * B_DIM + b) * C_DIM + ch) * N_DIM + n0g;
                float ov[4];
                #pragma unroll
                for (int j = 0; j < 4; j++) {
                    float y = __fadd_rn(acc[r * 4 + j], pb);
                    y = __fadd_rn(__fmul_rn(y, iv), bs);
                    ov[j] = lif_step(vstate[r * 4 + j], y, 1.0f);
                }
                float4 o4;
                o4.x = ov[0]; o4.y = ov[1]; o4.z = ov[2]; o4.w = ov[3];
                *(float4*)(ob + n0) = o4;
            }
            #pragma unroll
            for (int i = 0; i < 32; i++) acc[i] = 0.0f;
        }
    }
    #undef BITS_AT
}

extern "C" void kernel_launch(void* const* d_in, const int* in_sizes, int n_in,
                              void* d_out, int out_size, void* d_ws, size_t ws_size,
                              hipStream_t stream) {
    const float* x    = (const float*)d_in[0];
    const float* q_w  = (const float*)d_in[1];
    const float* q_g  = (const float*)d_in[2];
    const float* q_b  = (const float*)d_in[3];
    const float* q_m  = (const float*)d_in[4];
    const float* q_v  = (const float*)d_in[5];
    const float* k_w  = (const float*)d_in[6];
    const float* k_g  = (const float*)d_in[7];
    const float* k_b  = (const float*)d_in[8];
    const float* k_m  = (const float*)d_in[9];
    const float* k_v  = (const float*)d_in[10];
    const float* p_w  = (const float*)d_in[11];
    const float* p_b  = (const float*)d_in[12];
    const float* p_g  = (const float*)d_in[13];
    const float* p_be = (const float*)d_in[14];
    const float* p_m  = (const float*)d_in[15];
    const float* p_v  = (const float*)d_in[16];

    // ws layout: wqk_t 512KB | p_t 256KB | xbits 4MB
    float*    wqk_t = (float*)d_ws;
    float*    p_t   = (float*)((char*)d_ws + 524288);
    uint32_t* xbits = (uint32_t*)((char*)d_ws + 786432);
    float*    out   = (float*)d_out;

    k_transpose<<<768, 256, 0, stream>>>(q_w, k_w, p_w, wqk_t, p_t);

    dim3 g1(NHEAD / 2, N_DIM / 128, B_DIM);
    k_qk<<<g1, 512, 0, stream>>>(x, wqk_t, q_g, q_b, q_m, q_v,
                                 k_g, k_b, k_m, k_v, xbits);

    dim3 g2(C_DIM / 128, N_DIM / 128, B_DIM);
    k_proj<<<g2, 512, 0, stream>>>(xbits, p_t, p_b, p_g, p_be, p_m, p_v, out);
}

// Round 7
// 846.380 us; speedup vs baseline: 3.3676x; 1.0006x over previous
//
#include <hip/hip_runtime.h>
#include <cstdint>
#include <cstddef>

#define T_DIM 4
#define B_DIM 32
#define C_DIM 256
#define N_DIM 1024
#define NHEAD 8
#define DHEAD 32
#define NWRD 32   // N/32 bit-words per row

// LIF step, exact reference rounding: v += (x-v)/2; s = v>=vth; hard reset.
__device__ __forceinline__ float lif_step(float& v, float x, float vth) {
    v = __fadd_rn(v, __fmul_rn(__fsub_rn(x, v), 0.5f));
    const float s = (v >= vth) ? 1.0f : 0.0f;
    if (s != 0.0f) v = 0.0f;
    return s;
}

// async global->LDS, 16B per lane. LDS dest = wave-uniform base + lane*16.
__device__ __forceinline__ void async_copy16(const float* g, float* l) {
    __builtin_amdgcn_global_load_lds(
        (const __attribute__((address_space(1))) unsigned int*)g,
        (__attribute__((address_space(3))) unsigned int*)l, 16, 0, 0);
}

// one a-element times 4 cols, strict k-ascending chains per acc element
#define FMA_ROW4(r, av)                               \
    acc[(r)*4+0] = fmaf(av, b0.x, acc[(r)*4+0]);      \
    acc[(r)*4+1] = fmaf(av, b0.y, acc[(r)*4+1]);      \
    acc[(r)*4+2] = fmaf(av, b0.z, acc[(r)*4+2]);      \
    acc[(r)*4+3] = fmaf(av, b0.w, acc[(r)*4+3]);

#define FMA_8x4()        \
    FMA_ROW4(0, a0.x)    \
    FMA_ROW4(1, a0.y)    \
    FMA_ROW4(2, a0.z)    \
    FMA_ROW4(3, a0.w)    \
    FMA_ROW4(4, a1.x)    \
    FMA_ROW4(5, a1.y)    \
    FMA_ROW4(6, a1.z)    \
    FMA_ROW4(7, a1.w)

// Pre-transpose: wqk_t[k][h*64+j] = (j<32 ? qw[h*32+j][k] : kw[h*32+j-32][k])
//                p_t[k][c] = pw[c][k]
__global__ __launch_bounds__(256) void k_transpose(
    const float* __restrict__ qw, const float* __restrict__ kw,
    const float* __restrict__ pw, float* __restrict__ wqk_t,
    float* __restrict__ p_t)
{
    const int i = blockIdx.x * 256 + threadIdx.x;
    if (i < C_DIM * 512) {
        const int k = i >> 9, col = i & 511;
        const int h = col >> 6, j = col & 63;
        wqk_t[i] = (j < 32) ? qw[(size_t)(h * 32 + j) * C_DIM + k]
                            : kw[(size_t)(h * 32 + j - 32) * C_DIM + k];
    } else {
        const int i2 = i - C_DIM * 512;            // < 65536
        const int k = i2 >> 8, c = i2 & 255;
        p_t[i2] = pw[(size_t)c * C_DIM + k];
    }
}

// K1: 2 heads per block. grid (NHEAD/2, N/128, B), block 512.
// Block tile m=128, n=128, BK=16; thread tile 8x4. BK=16 cuts LDS to ~35KB ->
// 4 blocks/CU; with VGPR=64 (round-5 measured, spill-free) that is 32
// waves/CU -- double round 5's TLP. Same k-ascending fmaf chains (bit-exact);
// only chunk granularity changed. ONE barrier per chunk; 64 chunks = 4t x 16k.
__global__ __launch_bounds__(512, 4) void k_qk(
    const float* __restrict__ x, const float* __restrict__ wqk,   // [256][512]
    const float* __restrict__ qg, const float* __restrict__ qbeta,
    const float* __restrict__ qmean, const float* __restrict__ qvar,
    const float* __restrict__ kg, const float* __restrict__ kbeta,
    const float* __restrict__ kmean, const float* __restrict__ kvar,
    uint32_t* __restrict__ xbits)
{
    __shared__ float w_lds[2][16 * 128];   // [buf][k][m] 2x8 KB
    __shared__ float x_lds[2][16 * 128];   // [buf][k][n] 2x8 KB
    __shared__ float inv_lds[128];
    __shared__ float bias_lds[128];
    __shared__ float    qsum_lds[256];     // dedicated epilogue scratch
    __shared__ float    attn_lds[256];
    __shared__ uint32_t pack_lds[256];

    const int tid = threadIdx.x;
    const int hp = blockIdx.x, nt = blockIdx.y, b = blockIdx.z;
    const int n0g = nt * 128;

    const int  mg   = tid >> 5;        // 0..15 -> rows mg*8..+7
    const int  m0   = mg << 3;
    const int  ng   = tid & 31;
    const int  n0   = ng << 2;         // cols n0..n0+3
    const int  hsel = mg >> 3;
    const bool is_q = ((mg & 7) < 4);  // wave-uniform (mg pairs per wave)

    if (tid < 128) {
        const int m = tid;
        const int hs = m >> 6, j = m & 63;
        const int h = hp * 2 + hs;
        const bool q = (j < 32);
        const float* g  = q ? qg    : kg;
        const float* be = q ? qbeta : kbeta;
        const float* me = q ? qmean : kmean;
        const float* va = q ? qvar  : kvar;
        const int ch = h * DHEAD + (q ? j : j - 32);
        const float iv = __fdiv_rn(g[ch], __fsqrt_rn(__fadd_rn(va[ch], 1e-5f)));
        inv_lds[m]  = iv;
        bias_lds[m] = __fsub_rn(be[ch], __fmul_rn(me[ch], iv));
    }

    // staging: thread covers k-row skl, cols scol..+3; dst = tid*4 (wave-linear)
    const int skl  = tid >> 5;         // 0..15
    const int scol = (tid & 31) << 2;
    const float* wgp = wqk + (size_t)skl * 512 + hp * 128 + scol;

    float vstate[32];
    #pragma unroll
    for (int i = 0; i < 32; i++) vstate[i] = 0.0f;
    float v_attn = 0.0f;

    // stage chunk 0 into buf 0
    {
        const float* xgp = x + ((size_t)b * C_DIM + skl) * N_DIM + n0g + scol;
        async_copy16(wgp,  &w_lds[0][tid * 4]);
        async_copy16(xgp,  &x_lds[0][tid * 4]);
    }

    float acc[32];
    #pragma unroll
    for (int i = 0; i < 32; i++) acc[i] = 0.0f;

    for (int g = 0; g < 64; ++g) {
        const int cur = g & 1;
        __syncthreads();   // drains stage(g) (in flight a full compute phase);
                           // joins readers of buf[1-cur] (chunk g-1)
        if (g + 1 < 64) {  // stage chunk g+1 into the other buffer
            const int g1 = g + 1, tt = g1 >> 4, kk = (g1 & 15) * 16;
            const float* xgp = x + ((size_t)(tt * B_DIM + b) * C_DIM + kk + skl) * N_DIM
                               + n0g + scol;
            async_copy16(wgp + (size_t)kk * 512, &w_lds[1 - cur][tid * 4]);
            async_copy16(xgp,                    &x_lds[1 - cur][tid * 4]);
        }
        {
            const float* wl = &w_lds[cur][0];
            const float* xl = &x_lds[cur][0];
            #pragma unroll 2
            for (int k = 0; k < 16; k++) {
                const float4 a0 = *(const float4*)(wl + k * 128 + m0);
                const float4 a1 = *(const float4*)(wl + k * 128 + m0 + 4);
                const float4 b0 = *(const float4*)(xl + k * 128 + n0);
                FMA_8x4()
            }
        }

        if ((g & 15) == 15) {   // end of one t: BN + LIF + attn + pack epilogue
            const int t = g >> 4;
            #pragma unroll
            for (int r = 0; r < 8; r++) {
                const float iv = inv_lds[m0 + r];
                const float bs = bias_lds[m0 + r];
                #pragma unroll
                for (int j = 0; j < 4; j++) {
                    const float y = __fadd_rn(__fmul_rn(acc[r * 4 + j], iv), bs);
                    acc[r * 4 + j] = lif_step(vstate[r * 4 + j], y, 1.0f);
                }
            }
            if (tid < 256) { qsum_lds[tid] = 0.0f; pack_lds[tid] = 0u; }
            __syncthreads();
            if (is_q) {
                #pragma unroll
                for (int j = 0; j < 4; j++) {
                    const int col = n0 + j;
                    float cs = acc[j];
                    #pragma unroll
                    for (int r = 1; r < 8; r++) cs += acc[r * 4 + j];
                    atomicAdd(&qsum_lds[hsel * 128 + col], cs);
                }
            }
            __syncthreads();
            if (tid < 256) attn_lds[tid] = lif_step(v_attn, qsum_lds[tid], 0.5f);
            __syncthreads();
            if (!is_q) {
                #pragma unroll
                for (int r = 0; r < 8; r++) {
                    const int krow = ((mg & 7) - 4) * 8 + r;
                    uint32_t nib = 0;
                    #pragma unroll
                    for (int jj = 0; jj < 4; jj++) {
                        if (acc[r * 4 + jj] != 0.0f &&
                            attn_lds[hsel * 128 + n0 + jj] != 0.0f)
                            nib |= (1u << jj);
                    }
                    if (nib) {
                        const int word = ng >> 3;
                        const int shf  = (ng & 7) * 4;
                        atomicOr(&pack_lds[hsel * 128 + krow * 4 + word], nib << shf);
                    }
                }
            }
            __syncthreads();
            if (tid < 256) {
                const int hs2  = tid >> 7;
                const int rem  = tid & 127;
                const int krow = rem >> 2, word = rem & 3;
                const int ch = (hp * 2 + hs2) * DHEAD + krow;
                xbits[((size_t)(t * B_DIM + b) * C_DIM + ch) * NWRD + nt * 4 + word]
                    = pack_lds[tid];
            }
            // reset acc for next t (registers)
            #pragma unroll
            for (int i = 0; i < 32; i++) acc[i] = 0.0f;
            // next loop-top barrier protects scratch before next epilogue
        }
    }
}

// K2: projection GEMM. grid (C/128, N/128, B), block 512.  (unchanged from
// round 5 -- verified; k_qk's drop should surface k_proj in the profile.)
// Block tile m=128, n=128, BK=32; thread tile 8x4. Double-buffered w (async)
// + x (bit-unpack to LDS, 8 floats/thread); bits pipelined 2 chunks ahead.
// ONE barrier per chunk; epilogue uses no LDS (no barriers).
__global__ __launch_bounds__(512, 4) void k_proj(
    const uint32_t* __restrict__ xbits, const float* __restrict__ pt,  // [256][256]
    const float* __restrict__ pbias, const float* __restrict__ pg,
    const float* __restrict__ pbeta, const float* __restrict__ pmean,
    const float* __restrict__ pvar, float* __restrict__ out)
{
    __shared__ float w_lds[2][32 * 128];
    __shared__ float x_lds[2][32 * 128];
    __shared__ float inv_lds[128];
    __shared__ float bias_lds[128];
    __shared__ float pb_lds[128];

    const int tid = threadIdx.x;
    const int mt = blockIdx.x, nt = blockIdx.y, b = blockIdx.z;
    const int n0g = nt * 128;
    const int c0  = mt * 128;

    const int mg = tid >> 5, m0 = mg << 3;
    const int ng = tid & 31, n0 = ng << 2;

    if (tid < 128) {
        const int ch = c0 + tid;
        const float iv = __fdiv_rn(pg[ch], __fsqrt_rn(__fadd_rn(pvar[ch], 1e-5f)));
        inv_lds[tid]  = iv;
        bias_lds[tid] = __fsub_rn(pbeta[ch], __fmul_rn(pmean[ch], iv));
        pb_lds[tid]   = pbias[ch];
    }

    const int skl  = tid >> 5;
    const int scol = (tid & 31) << 2;
    const float* wgp = pt + (size_t)skl * 256 + c0 + scol;

    // unpack: thread -> chunk k-row urow (0..31), 8 cols at cg*8
    const int urow = tid >> 4, cg = tid & 15;
    const int wsel = nt * 4 + (cg >> 2);
    const int ushf = (cg & 3) * 8;

    float vstate[32];
    #pragma unroll
    for (int i = 0; i < 32; i++) vstate[i] = 0.0f;

    // bits word for global chunk G: xbits[((G>>3)*B+b)*C*NWRD + ((G&7)*32+urow)*NWRD + wsel]
    #define BITS_AT(G) xbits[((size_t)((G) >> 3) * B_DIM + b) * C_DIM * NWRD \
                             + (size_t)(((G) & 7) * 32 + urow) * NWRD + wsel]

    // prologue: unpack chunk 0 + stage w(0) into buf0; preload bits(1)
    {
        const uint32_t u0 = BITS_AT(0);
        const uint32_t bits = (u0 >> ushf) & 0xffu;
        float* xw = &x_lds[0][urow * 128 + cg * 8];
        float4 f0, f1;
        f0.x = ((bits >> 0) & 1u) ? 1.0f : 0.0f;
        f0.y = ((bits >> 1) & 1u) ? 1.0f : 0.0f;
        f0.z = ((bits >> 2) & 1u) ? 1.0f : 0.0f;
        f0.w = ((bits >> 3) & 1u) ? 1.0f : 0.0f;
        f1.x = ((bits >> 4) & 1u) ? 1.0f : 0.0f;
        f1.y = ((bits >> 5) & 1u) ? 1.0f : 0.0f;
        f1.z = ((bits >> 6) & 1u) ? 1.0f : 0.0f;
        f1.w = ((bits >> 7) & 1u) ? 1.0f : 0.0f;
        *(float4*)(xw)     = f0;
        *(float4*)(xw + 4) = f1;
        #pragma unroll
        for (int r = 0; r < 2; r++)
            async_copy16(wgp + (size_t)(r * 16) * 256, &w_lds[0][r * 2048 + tid * 4]);
    }
    uint32_t u_a = BITS_AT(1);

    float acc[32];
    #pragma unroll
    for (int i = 0; i < 32; i++) acc[i] = 0.0f;

    for (int g = 0; g < 32; ++g) {
        const int cur = g & 1;
        __syncthreads();   // drains unpack writes + w copies for chunk g;
                           // joins readers of buf[1-cur]
        if (g + 1 < 32) {  // prepare chunk g+1 in the other buffer
            const int kk = ((g + 1) & 7) * 32;
            const uint32_t bits = (u_a >> ushf) & 0xffu;
            float* xw = &x_lds[1 - cur][urow * 128 + cg * 8];
            float4 f0, f1;
            f0.x = ((bits >> 0) & 1u) ? 1.0f : 0.0f;
            f0.y = ((bits >> 1) & 1u) ? 1.0f : 0.0f;
            f0.z = ((bits >> 2) & 1u) ? 1.0f : 0.0f;
            f0.w = ((bits >> 3) & 1u) ? 1.0f : 0.0f;
            f1.x = ((bits >> 4) & 1u) ? 1.0f : 0.0f;
            f1.y = ((bits >> 5) & 1u) ? 1.0f : 0.0f;
            f1.z = ((bits >> 6) & 1u) ? 1.0f : 0.0f;
            f1.w = ((bits >> 7) & 1u) ? 1.0f : 0.0f;
            *(float4*)(xw)     = f0;
            *(float4*)(xw + 4) = f1;
            float* wd = &w_lds[1 - cur][0];
            #pragma unroll
            for (int r = 0; r < 2; r++)
                async_copy16(wgp + (size_t)(kk + r * 16) * 256, wd + r * 2048 + tid * 4);
        }
        if (g + 2 < 32) u_a = BITS_AT(g + 2);   // hidden under compute(g)
        {
            const float* wl = &w_lds[cur][0];
            const float* xl = &x_lds[cur][0];
            #pragma unroll 2
            for (int k = 0; k < 32; k++) {
                const float4 a0 = *(const float4*)(wl + k * 128 + m0);
                const float4 a1 = *(const float4*)(wl + k * 128 + m0 + 4);
                const float4 b0 = *(const float4*)(xl + k * 128 + n0);
                FMA_8x4()
            }
        }

        if ((g & 7) == 7) {   // end of t: bias + BN + LIF + store (regs + global)
            const int t = g >> 3;
            #pragma unroll
            for (int r = 0; r < 8; r++) {
                const int ch = c0 + m0 + r;
                const float iv = inv_lds[m0 + r];
                const float bs = bias_lds[m0 + r];
                const float pb = pb_lds[m0 + r];
                float* ob = out + ((size_t)(t * B_DIM + b) * C_DIM + ch) * N_DIM + n0g;
                float ov[4];
                #pragma unroll
                for (int j = 0; j < 4; j++) {
                    float y = __fadd_rn(acc[r * 4 + j], pb);
                    y = __fadd_rn(__fmul_rn(y, iv), bs);
                    ov[j] = lif_step(vstate[r * 4 + j], y, 1.0f);
                }
                float4 o4;
                o4.x = ov[0]; o4.y = ov[1]; o4.z = ov[2]; o4.w = ov[3];
                *(float4*)(ob + n0) = o4;
            }
            #pragma unroll
            for (int i = 0; i < 32; i++) acc[i] = 0.0f;
        }
    }
    #undef BITS_AT
}

extern "C" void kernel_launch(void* const* d_in, const int* in_sizes, int n_in,
                              void* d_out, int out_size, void* d_ws, size_t ws_size,
                              hipStream_t stream) {
    const float* x    = (const float*)d_in[0];
    const float* q_w  = (const float*)d_in[1];
    const float* q_g  = (const float*)d_in[2];
    const float* q_b  = (const float*)d_in[3];
    const float* q_m  = (const float*)d_in[4];
    const float* q_v  = (const float*)d_in[5];
    const float* k_w  = (const float*)d_in[6];
    const float* k_g  = (const float*)d_in[7];
    const float* k_b  = (const float*)d_in[8];
    const float* k_m  = (const float*)d_in[9];
    const float* k_v  = (const float*)d_in[10];
    const float* p_w  = (const float*)d_in[11];
    const float* p_b  = (const float*)d_in[12];
    const float* p_g  = (const float*)d_in[13];
    const float* p_be = (const float*)d_in[14];
    const float* p_m  = (const float*)d_in[15];
    const float* p_v  = (const float*)d_in[16];

    // ws layout: wqk_t 512KB | p_t 256KB | xbits 4MB
    float*    wqk_t = (float*)d_ws;
    float*    p_t   = (float*)((char*)d_ws + 524288);
    uint32_t* xbits = (uint32_t*)((char*)d_ws + 786432);
    float*    out   = (float*)d_out;

    k_transpose<<<768, 256, 0, stream>>>(q_w, k_w, p_w, wqk_t, p_t);

    dim3 g1(NHEAD / 2, N_DIM / 128, B_DIM);
    k_qk<<<g1, 512, 0, stream>>>(x, wqk_t, q_g, q_b, q_m, q_v,
                                 k_g, k_b, k_m, k_v, xbits);

    dim3 g2(C_DIM / 128, N_DIM / 128, B_DIM);
    k_proj<<<g2, 512, 0, stream>>>(xbits, p_t, p_b, p_g, p_be, p_m, p_v, out);
}